// Round 1
// baseline (608.414 us; speedup 1.0000x reference)
//
#include <hip/hip_runtime.h>
#include <cstdint>

#define B_   8
#define K_   512
#define DAPP 768
#define DK   96
#define DG   96

// ws layout (floats):
//   [0,      P)  : w_k   [B*K][96]
//   [P,     2P)  : w_q   [B*K][96]
//   [2P,    3P)  : w_v   [B*K][96]
//   [3P, 3P+BKK) : logits [B*K][K]   (indexed [b*K+m][n])
#define P_F ((size_t)B_ * K_ * DK)          // 393216 floats
#define LG_OFF (3 * P_F)

__device__ __forceinline__ float dot4(float4 a, float4 b) {
    return a.x * b.x + a.y * b.y + a.z * b.z + a.w * b.w;
}

// ---------------------------------------------------------------------------
// Kernel 1: w_k / w_q / w_v projections.  grid (256, 3), block 256.
// Each block: 16 rows of f_a; thread (tr,tc) -> row tr, cols {tc+16j, j=0..5}.
// A-loads broadcast across the 16 tc lanes; W rows live in L1/L2.
// ---------------------------------------------------------------------------
__global__ __launch_bounds__(256) void proj_kernel(
    const float* __restrict__ fa,
    const float* __restrict__ WK, const float* __restrict__ WKb,
    const float* __restrict__ WQ, const float* __restrict__ WQb,
    const float* __restrict__ WV, const float* __restrict__ WVb,
    float* __restrict__ ws) {
    const int mat = blockIdx.y;
    const float* W  = (mat == 0) ? WK  : (mat == 1) ? WQ  : WV;
    const float* Wb = (mat == 0) ? WKb : (mat == 1) ? WQb : WVb;
    float* outp = ws + (size_t)mat * P_F;

    const int t  = threadIdx.x;
    const int tr = t >> 4;        // 0..15 : row within tile
    const int tc = t & 15;        // 0..15 : col group
    const int row = blockIdx.x * 16 + tr;

    const float4* fa4 = (const float4*)fa + (size_t)row * (DAPP / 4);
    const float4* W4  = (const float4*)W;

    float acc[6] = {0.f, 0.f, 0.f, 0.f, 0.f, 0.f};
    const float4* wrow[6];
#pragma unroll
    for (int j = 0; j < 6; ++j)
        wrow[j] = W4 + (size_t)(tc + 16 * j) * (DAPP / 4);

#pragma unroll 2
    for (int q = 0; q < DAPP / 4; ++q) {
        float4 a = fa4[q];
#pragma unroll
        for (int j = 0; j < 6; ++j)
            acc[j] += dot4(a, wrow[j][q]);
    }
#pragma unroll
    for (int j = 0; j < 6; ++j) {
        int c = tc + 16 * j;
        outp[(size_t)row * DK + c] = acc[j] + Wb[c];
    }
}

// ---------------------------------------------------------------------------
// Kernel 2: logits[b,m,n] = log(max(PE[b,m,n,:]·WG + gb, 1e-6))
//                           + (w_k[b,m]·w_q[b,n]) / sqrt(96)
// grid 4096 = B*K (one block per (b,m)), block 256.
// 8 lanes per n; lane p owns float4 fragments {p, p+8, p+16} of the 24-f4 row
// -> each load instruction is perfectly line-coalesced (8 n * 128B clusters).
// ---------------------------------------------------------------------------
__global__ __launch_bounds__(256) void logits_kernel(
    const float* __restrict__ pe,
    const float* __restrict__ WGw, const float* __restrict__ WGb,
    float* ws) {
    const int bm = blockIdx.x;           // b*K + m
    const int b  = bm >> 9;

    const int t = threadIdx.x;
    const int p = t & 7;                 // 0..7: fragment lane
    const int nidx = t >> 3;             // 0..31: n within tile

    const float4* wk4 = (const float4*)ws + (size_t)bm * 24;
    const float4* wq4 = (const float4*)(ws + P_F);
    const float4* wg4 = (const float4*)WGw;
    const float4* pe4 = (const float4*)pe + (size_t)bm * K_ * 24;
    float* lg = ws + LG_OFF + (size_t)bm * K_;

    // per-lane weight fragments (stride-8 f4 assignment)
    float4 kf0 = wk4[p], kf1 = wk4[p + 8], kf2 = wk4[p + 16];
    float4 gf0 = wg4[p], gf1 = wg4[p + 8], gf2 = wg4[p + 16];
    const float gb = WGb[0];
    const float inv_sqrt_dk = 0.10206207f;   // 1/sqrt(96)

    for (int it = 0; it < 16; ++it) {
        const int n = it * 32 + nidx;
        const float4* pr = pe4 + (size_t)n * 24 + p;
        float s1 = dot4(pr[0], gf0) + dot4(pr[8], gf1) + dot4(pr[16], gf2);
        const float4* qr = wq4 + ((size_t)(b * K_ + n)) * 24 + p;
        float s2 = dot4(qr[0], kf0) + dot4(qr[8], kf1) + dot4(qr[16], kf2);
        // reduce over the 8-lane group (bits 0..2 of lane id)
        s1 += __shfl_xor(s1, 1); s2 += __shfl_xor(s2, 1);
        s1 += __shfl_xor(s1, 2); s2 += __shfl_xor(s2, 2);
        s1 += __shfl_xor(s1, 4); s2 += __shfl_xor(s2, 4);
        if (p == 0) {
            float gate = fmaxf(s1 + gb, 1e-6f);   // relu + clip combined
            lg[n] = __logf(gate) + s2 * inv_sqrt_dk;
        }
    }
}

// ---------------------------------------------------------------------------
// Kernel 3: softmax over m (per column n) + PV.
// grid B*32 (16-column n-tile per block), block 384.
// LDS tile [512][20] (stride 20 -> 2-way conflicts only, float4-aligned).
// ---------------------------------------------------------------------------
__global__ __launch_bounds__(384) void softmax_pv_kernel(
    const float* __restrict__ ws_c, float* __restrict__ out) {
    __shared__ __align__(16) float sp[512 * 20];
    const int blk = blockIdx.x;
    const int b = blk >> 5;
    const int n0 = (blk & 31) * 16;
    const int t = threadIdx.x;

    const float* logits = ws_c + LG_OFF + (size_t)b * K_ * K_;
    const float4* lg4 = (const float4*)logits;

    // load 512 x 16 logit tile (4 f4 per m-row)
    for (int i = t; i < 2048; i += 384) {
        int mrow = i >> 2, q = i & 3;
        float4 v = lg4[(size_t)mrow * (K_ / 4) + (n0 >> 2) + q];
        *(float4*)&sp[mrow * 20 + q * 4] = v;
    }
    __syncthreads();

    // softmax over m: 16 lanes per column, 16 columns (threads 0..255)
    if (t < 256) {
        const int c = t >> 4, l = t & 15;
        float vals[32];
        float mx = -1e30f;
#pragma unroll
        for (int i = 0; i < 32; ++i) {
            vals[i] = sp[(i * 16 + l) * 20 + c];
            mx = fmaxf(mx, vals[i]);
        }
        mx = fmaxf(mx, __shfl_xor(mx, 8));
        mx = fmaxf(mx, __shfl_xor(mx, 4));
        mx = fmaxf(mx, __shfl_xor(mx, 2));
        mx = fmaxf(mx, __shfl_xor(mx, 1));
        float sum = 0.f;
#pragma unroll
        for (int i = 0; i < 32; ++i) {
            float e = __expf(vals[i] - mx);
            vals[i] = e;
            sum += e;
        }
        sum += __shfl_xor(sum, 8);
        sum += __shfl_xor(sum, 4);
        sum += __shfl_xor(sum, 2);
        sum += __shfl_xor(sum, 1);
        float inv = 1.f / sum;
#pragma unroll
        for (int i = 0; i < 32; ++i)
            sp[(i * 16 + l) * 20 + c] = vals[i] * inv;
    }
    __syncthreads();

    // PV: out[b, n0+g*4+j, d] = sum_m p[m][g*4+j] * wv[b,m,d]
    const int d = t % 96;
    const int g = t / 96;                 // 0..3
    const float* wv = ws_c + 2 * P_F + (size_t)b * K_ * DK;
    float a0 = 0.f, a1 = 0.f, a2 = 0.f, a3 = 0.f;
#pragma unroll 8
    for (int mrow = 0; mrow < 512; ++mrow) {
        float v = wv[(size_t)mrow * DK + d];
        float4 p4 = *(const float4*)&sp[mrow * 20 + g * 4];
        a0 += p4.x * v; a1 += p4.y * v; a2 += p4.z * v; a3 += p4.w * v;
    }
    const int nbase = n0 + g * 4;
    float* ob = out + ((size_t)b * K_ + nbase) * DK + d;
    ob[0]      = a0;
    ob[DK]     = a1;
    ob[2 * DK] = a2;
    ob[3 * DK] = a3;
}

// ---------------------------------------------------------------------------
extern "C" void kernel_launch(void* const* d_in, const int* in_sizes, int n_in,
                              void* d_out, int out_size, void* d_ws, size_t ws_size,
                              hipStream_t stream) {
    (void)in_sizes; (void)n_in; (void)out_size; (void)ws_size;
    const float* fa  = (const float*)d_in[0];
    const float* pe  = (const float*)d_in[1];
    const float* WGw = (const float*)d_in[2];
    const float* WGb = (const float*)d_in[3];
    const float* WKw = (const float*)d_in[4];
    const float* WKb = (const float*)d_in[5];
    const float* WQw = (const float*)d_in[6];
    const float* WQb = (const float*)d_in[7];
    const float* WVw = (const float*)d_in[8];
    const float* WVb = (const float*)d_in[9];
    float* out = (float*)d_out;
    float* ws  = (float*)d_ws;

    proj_kernel<<<dim3(256, 3), 256, 0, stream>>>(fa, WKw, WKb, WQw, WQb, WVw, WVb, ws);
    logits_kernel<<<B_ * K_, 256, 0, stream>>>(pe, WGw, WGb, ws);
    softmax_pv_kernel<<<B_ * 32, 384, 0, stream>>>(ws, out);
}